// Round 8
// baseline (37971.802 us; speedup 1.0000x reference)
//
#include <hip/hip_runtime.h>
#include <hip/hip_fp16.h>

// B=256, T=512, F=16, H=256, L=2 LSTM + gather(len-1) + ReLU + FC(256->1).
//
// R16: R15 (proven 195us steady, passed) with the K-split replaced by a
// GATE-PAIR split. Thread = (u, gp): computes gates {2gp,2gp+1} over full
// K=256. Weights repacked [gp][64 P][256 u][(2g x 2pair) float4] so the
// inner loop keeps R15's exact 4-slot ring shape (64 b128/step/thread,
// prefetch distance 3, wraps across steps). What this buys vs R15:
//  - partial exchange = 2 __shfl_xor(.,1) per batch (lane pairs share u);
//    the 24-LDS-op scratch round-trip per step is gone
//  - epilogue on ALL 512 threads (duplicated per lane pair, cheap) instead
//    of the kh==0-only serial half
//  - ONE lds_barrier per step instead of two
// R12/R15 proved load scheduling is NOT the wall (-2% each); the ~5-6K
// cy/step above the 8.7K stream floor is sync structure -- this attacks it.
// Live set < R15 (6 accs vs 12; same 64-VGPR ring): spill-safe.
//   blocks   0..85 : l0 recurrence, chunk k
//   blocks  86..171: l1 recurrence, chunk k-2 (reads precomputed xp1)
//   blocks 172..235: gemm xp1 = W_ih1 @ h0 + b1, chunk k-1
// Tc=32, 16 chunks, 18 launches.

#define Tc 32
#define NCHUNK 16

// fp32 region (float offsets)
#define OFF_IH0   0        // REPACKED fp16: [8 pair][256 u][4 g][2] (32 KB)
#define OFF_B0    16384    // [256 u][4 g] = b_ih0+b_hh0
#define OFF_B1    17408    // [256 u][4 g] = b_ih1+b_hh1
#define OFF_C0S   18432    // [258][256] l0 cell state
#define OFF_C1S   84480    // [258][256] l1 cell state
#define OFF_H1S   150528   // [258][256] l1 h state
#define OFF_HLAST 216576   // [258][256]
#define FP_END    282624
// fp16 region (half offsets from h16 = (half*)(ws+FP_END))
#define H_HH0  0           // NEW: [2 gp][64 P][256 u][(2g x 2pr) = 8 halves]
#define H_HH1  262144      // same layout
#define H_IH1  524288      // OLD: [p][u][g][2] (gemm streams it)
#define H_H0C  786432      // [2 slot][258 b][32 t][256 u]
#define H0SLOT 2113536
#define H_XP1  5013504     // [2 slot][258 b][32 t][1024 (u*4+g)]
#define XPSLOT 8454144
// end 21921792 halves; total ws ~= 45.0 MB

#define SMEM_BYTES 66560   // gemm needs 65536 (hc2); l0 ~37 KB; l1 ~4 KB

typedef _Float16 v2h __attribute__((ext_vector_type(2)));

__device__ __forceinline__ unsigned packh2(float a, float b) {
  __half2 h = __floats2half2_rn(a, b);
  return *(unsigned*)&h;
}
// w = (g0:prA, g0:prB, g1:prA, g1:prB); hx = h[prA], hy = h[prB]
__device__ __forceinline__ void dotg2(const float4 w, const v2h hx, const v2h hy,
                                      float& a0, float& a1) {
  const v2h* wp = (const v2h*)&w;
  a0 = __builtin_amdgcn_fdot2(wp[0], hx, a0, false);
  a0 = __builtin_amdgcn_fdot2(wp[1], hy, a0, false);
  a1 = __builtin_amdgcn_fdot2(wp[2], hx, a1, false);
  a1 = __builtin_amdgcn_fdot2(wp[3], hy, a1, false);
}
__device__ __forceinline__ float sigf(float x) {
  return __fdividef(1.f, 1.f + __expf(-x));
}
__device__ __forceinline__ float tanhf_fast(float x) {
  float ax = fabsf(x);
  float e = __expf(-2.f * ax);
  float t = __fdividef(1.f - e, 1.f + e);
  return copysignf(t, x);
}
__device__ __forceinline__ float h2f(unsigned short s) {
  __half h = __builtin_bit_cast(__half, s);
  return __half2float(h);
}
__device__ __forceinline__ v2h u2h(unsigned v) {
  return __builtin_bit_cast(v2h, v);
}
// LDS-only barrier: orders DS traffic without __syncthreads' vmcnt(0) drain.
__device__ __forceinline__ void lds_barrier() {
  asm volatile("s_waitcnt lgkmcnt(0)" ::: "memory");
  __builtin_amdgcn_s_barrier();
  __builtin_amdgcn_sched_barrier(0);
}

__global__ __launch_bounds__(256) void prep_kernel(
    const float* __restrict__ w_ih0, const float* __restrict__ w_hh0,
    const float* __restrict__ b_ih0, const float* __restrict__ b_hh0,
    const float* __restrict__ w_ih1, const float* __restrict__ w_hh1,
    const float* __restrict__ b_ih1, const float* __restrict__ b_hh1,
    float* __restrict__ ws) {
  const int idx = blockIdx.x * blockDim.x + threadIdx.x;  // [0,131072)
  unsigned* h16u = (unsigned*)(ws + FP_END);
  // NEW W_hh layout: u32 idx = gp*65536 + P*1024 + u*4 + q
  //   q: 0=(g 2gp, pair 2P) 1=(g 2gp, pair 2P+1) 2=(g 2gp+1, 2P) 3=(.., 2P+1)
  {
    const int q = idx & 3, u = (idx >> 2) & 255, P = (idx >> 10) & 63;
    const int gp = idx >> 16;
    const int g = 2 * gp + (q >> 1), pr = 2 * P + (q & 1);
    const int row = g * 256 + u, k0 = 2 * pr;
    h16u[H_HH0 / 2 + idx] = packh2(w_hh0[row * 256 + k0], w_hh0[row * 256 + k0 + 1]);
    h16u[H_HH1 / 2 + idx] = packh2(w_hh1[row * 256 + k0], w_hh1[row * 256 + k0 + 1]);
  }
  // OLD W_ih1 layout (gemm unchanged)
  {
    const int g = idx & 3, u = (idx >> 2) & 255, p = idx >> 10;
    const int j = g * 256 + u;
    h16u[H_IH1 / 2 + idx] = packh2(w_ih1[j * 256 + 2 * p], w_ih1[j * 256 + 2 * p + 1]);
  }
  if (idx < 8192) {  // w_ih0 fp16: [p<8][u][4 g][2] in OFF_IH0 space
    const int g = idx & 3, u = (idx >> 2) & 255, p = idx >> 10;
    const int j = g * 256 + u;
    ((unsigned*)(ws + OFF_IH0))[idx] =
        packh2(w_ih0[j * 16 + 2 * p], w_ih0[j * 16 + 2 * p + 1]);
  }
  if (idx < 1024) {
    const int g = idx & 3, u = (idx >> 2) & 255;
    const int j = g * 256 + u;
    ws[OFF_B0 + idx] = b_ih0[j] + b_hh0[j];
    ws[OFF_B1 + idx] = b_ih1[j] + b_hh1[j];
  }
}

__global__ __launch_bounds__(512)
__attribute__((amdgpu_waves_per_eu(2, 2)))
void fused_kernel(
    float* __restrict__ ws, const float* __restrict__ x,
    const int* __restrict__ lengths, int step) {
  extern __shared__ __align__(16) char smem_raw[];
  const int bid = blockIdx.x;
  const int tid = threadIdx.x;
  __half* h16 = (__half*)(ws + FP_END);
  unsigned short* h0cS = (unsigned short*)(h16 + H_H0C);
  unsigned short* xpS = (unsigned short*)(h16 + H_XP1);

  if (bid < 86) {
    // ================= role: layer-0 recurrence, chunk kc = step ==========
    if (step >= NCHUNK) return;
    const int kc = step;
    const int gp = tid & 1, u = tid >> 1;   // thread: unit u, gate-pair gp
    const int bg = bid * 3;
    unsigned short* hb = (unsigned short*)smem_raw;      // [2][768]
    unsigned* xsp = (unsigned*)(smem_raw + 4096);        // [2][3][8] x pairs
    unsigned* wxu = (unsigned*)(smem_raw + 4352);        // [8 p][1024] 32 KB

    int len[3];
    #pragma unroll
    for (int b = 0; b < 3; ++b) len[b] = (bg + b < 256) ? lengths[bg + b] : 1;
    const int tmaxb = max(len[0], max(len[1], len[2]));
    if (kc * Tc >= tmaxb) return;
    const int tend = min(Tc, tmaxb - kc * Tc);
    const int slot = kc & 1, slotP = slot ^ 1;

    // stage w_ih0 fp16 into LDS (once per launch)
    {
      const float4* gwx = (const float4*)(ws + OFF_IH0);
      float4* wxl = (float4*)wxu;
      #pragma unroll
      for (int e = 0; e < 4; ++e) wxl[tid + e * 512] = gwx[tid + e * 512];
    }

    // this gate-pair's 64 P-groups, streamed via 4-slot ring
    const float4* wq = (const float4*)(h16 + H_HH0) + (size_t)(gp * 64) * 256 + u;
    const float b0 = ws[OFF_B0 + u * 4 + 2 * gp];
    const float b1 = ws[OFF_B0 + u * 4 + 2 * gp + 1];

    // prime ring: groups 0..2 (prefetch distance 3)
    float4 R[4][4];
    #pragma unroll
    for (int j = 0; j < 3; ++j)
      #pragma unroll
      for (int p = 0; p < 4; ++p) R[j][p] = wq[(j * 4 + p) * 256];

    float c[3] = {0.f, 0.f, 0.f};
    if (gp == 0) {
      #pragma unroll
      for (int b = 0; b < 3; ++b) {
        unsigned short hv = 0;
        if (kc > 0)
          hv = h0cS[(size_t)slotP * H0SLOT + ((size_t)(bg + b) * 32 + 31) * 256 + u];
        hb[0 * 768 + b * 256 + u] = hv;
      }
    }
    if (kc > 0) {
      #pragma unroll
      for (int b = 0; b < 3; ++b) c[b] = ws[OFF_C0S + (bg + b) * 256 + u];
    }
    if (tid < 24) {  // stage x pairs for t0
      int b = tid >> 3, i = tid & 7;
      int bb = min(bg + b, 255);
      const float* xp = x + (size_t)bb * 8192 + (kc * Tc) * 16;
      xsp[0 * 24 + b * 8 + i] = packh2(xp[2 * i], xp[2 * i + 1]);
    }
    __syncthreads();

    for (int tc = 0; tc < tend; ++tc) {
      const int cur = tc & 1, nxt = cur ^ 1;
      // issue x prefetch for t+1 early (global; hides under dots)
      float2 xf = make_float2(0.f, 0.f);
      if (tid < 24) {
        int b = tid >> 3, i = tid & 7;
        int bb = min(bg + b, 255);
        int tn = min(kc * Tc + tc + 1, 511);
        xf = *(const float2*)(x + (size_t)bb * 8192 + tn * 16 + 2 * i);
      }
      float a0[3] = {b0, b0, b0}, a1[3] = {b1, b1, b1};

      // x-part: 8 pairs x 2 gates from LDS
      #pragma unroll
      for (int p = 0; p < 8; ++p) {
        uint2 w01 = *(const uint2*)(wxu + p * 1024 + u * 4 + 2 * gp);
        v2h w0 = u2h(w01.x), w1 = u2h(w01.y);
        #pragma unroll
        for (int b = 0; b < 3; ++b) {
          v2h xv = u2h(xsp[cur * 24 + b * 8 + p]);
          a0[b] = __builtin_amdgcn_fdot2(w0, xv, a0[b], false);
          a1[b] = __builtin_amdgcn_fdot2(w1, xv, a1[b], false);
        }
      }

      const float4* h0r0 = (const float4*)(hb + cur * 768 + 0 * 256);
      const float4* h0r1 = (const float4*)(hb + cur * 768 + 1 * 256);
      const float4* h0r2 = (const float4*)(hb + cur * 768 + 2 * 256);

      // h-part: 16 groups (8 pairs each), 4-slot ring, distance 3, wraps
      #pragma unroll
      for (int j = 0; j < 16; ++j) {
        const int s = j & 3;
        float4 w0 = R[s][0], w1 = R[s][1], w2 = R[s][2], w3 = R[s][3];
        const int jn = (j + 3) & 15;
        R[(j + 3) & 3][0] = wq[(jn * 4 + 0) * 256];
        R[(j + 3) & 3][1] = wq[(jn * 4 + 1) * 256];
        R[(j + 3) & 3][2] = wq[(jn * 4 + 2) * 256];
        R[(j + 3) & 3][3] = wq[(jn * 4 + 3) * 256];
        float4 hA0 = h0r0[2 * j], hB0 = h0r0[2 * j + 1];
        float4 hA1 = h0r1[2 * j], hB1 = h0r1[2 * j + 1];
        float4 hA2 = h0r2[2 * j], hB2 = h0r2[2 * j + 1];
        const v2h* a = (const v2h*)&hA0; const v2h* bb_ = (const v2h*)&hB0;
        dotg2(w0, a[0], a[1], a0[0], a1[0]);
        dotg2(w1, a[2], a[3], a0[0], a1[0]);
        dotg2(w2, bb_[0], bb_[1], a0[0], a1[0]);
        dotg2(w3, bb_[2], bb_[3], a0[0], a1[0]);
        a = (const v2h*)&hA1; bb_ = (const v2h*)&hB1;
        dotg2(w0, a[0], a[1], a0[1], a1[1]);
        dotg2(w1, a[2], a[3], a0[1], a1[1]);
        dotg2(w2, bb_[0], bb_[1], a0[1], a1[1]);
        dotg2(w3, bb_[2], bb_[3], a0[1], a1[1]);
        a = (const v2h*)&hA2; bb_ = (const v2h*)&hB2;
        dotg2(w0, a[0], a[1], a0[2], a1[2]);
        dotg2(w1, a[2], a[3], a0[2], a1[2]);
        dotg2(w2, bb_[0], bb_[1], a0[2], a1[2]);
        dotg2(w3, bb_[2], bb_[3], a0[2], a1[2]);
      }

      // finalize: swap gate-pair halves within lane pair; all threads work
      #pragma unroll
      for (int b = 0; b < 3; ++b) {
        float p0 = __shfl_xor(a0[b], 1);
        float p1 = __shfl_xor(a1[b], 1);
        float gi = gp ? p0 : a0[b];
        float gf = gp ? p1 : a1[b];
        float gg = gp ? a0[b] : p0;
        float go = gp ? a1[b] : p1;
        c[b] = sigf(gf) * c[b] + sigf(gi) * tanhf_fast(gg);
        float h = sigf(go) * tanhf_fast(c[b]);
        if (gp == 0) {
          unsigned short hu = __half_as_ushort(__float2half(h));
          hb[nxt * 768 + b * 256 + u] = hu;
          h0cS[(size_t)slot * H0SLOT + ((size_t)(bg + b) * 32 + tc) * 256 + u] = hu;
        }
      }
      if (tid < 24) {  // publish x for t+1
        int b = tid >> 3, i = tid & 7;
        xsp[nxt * 24 + b * 8 + i] = packh2(xf.x, xf.y);
      }
      lds_barrier();
    }
    if (gp == 0) {
      #pragma unroll
      for (int b = 0; b < 3; ++b) ws[OFF_C0S + (bg + b) * 256 + u] = c[b];
    }

  } else if (bid < 172) {
    // ============ role: layer-1 recurrence, chunk kc = step-2 =============
    if (step < 2 || step >= NCHUNK + 2) return;
    const int kc = step - 2;
    const int gp = tid & 1, u = tid >> 1;
    const int bg = (bid - 86) * 3;
    unsigned short* h1b = (unsigned short*)smem_raw;  // [2][768]

    int len[3];
    #pragma unroll
    for (int b = 0; b < 3; ++b) len[b] = (bg + b < 256) ? lengths[bg + b] : 1;
    const int tmaxb = max(len[0], max(len[1], len[2]));
    if (kc * Tc >= tmaxb) return;
    const int tend = min(Tc, tmaxb - kc * Tc);
    const int slot = kc & 1;

    const float4* wq = (const float4*)(h16 + H_HH1) + (size_t)(gp * 64) * 256 + u;

    float4 R[4][4];
    #pragma unroll
    for (int j = 0; j < 3; ++j)
      #pragma unroll
      for (int p = 0; p < 4; ++p) R[j][p] = wq[(j * 4 + p) * 256];

    float c[3] = {0.f, 0.f, 0.f}, hout[3] = {0.f, 0.f, 0.f};
    if (gp == 0) {
      #pragma unroll
      for (int b = 0; b < 3; ++b) {
        float hv = (kc > 0) ? ws[OFF_H1S + (bg + b) * 256 + u] : 0.f;
        h1b[0 * 768 + b * 256 + u] = __half_as_ushort(__float2half(hv));
      }
    }
    if (kc > 0) {
      #pragma unroll
      for (int b = 0; b < 3; ++b) {
        c[b] = ws[OFF_C1S + (bg + b) * 256 + u];
        hout[b] = ws[OFF_H1S + (bg + b) * 256 + u];
      }
    }
    // xp1 (bias+W_ih1 h0 folded): u32 per (b,t) holding this thread's 2 gates
    const unsigned* xpu = (const unsigned*)(xpS + (size_t)slot * XPSLOT);
    unsigned xc[3], xn[3];
    #pragma unroll
    for (int b = 0; b < 3; ++b)
      xc[b] = xpu[((size_t)(bg + b) * 32 + 0) * 512 + u * 2 + gp];
    __syncthreads();

    for (int tc = 0; tc < tend; ++tc) {
      const int cur = tc & 1, nxt = cur ^ 1;
      if (tc + 1 < tend) {
        #pragma unroll
        for (int b = 0; b < 3; ++b)
          xn[b] = xpu[((size_t)(bg + b) * 32 + tc + 1) * 512 + u * 2 + gp];
      }
      float a0[3], a1[3];
      #pragma unroll
      for (int b = 0; b < 3; ++b) {
        a0[b] = h2f((unsigned short)(xc[b] & 0xffff));
        a1[b] = h2f((unsigned short)(xc[b] >> 16));
      }

      const float4* r0 = (const float4*)(h1b + cur * 768 + 0 * 256);
      const float4* r1 = (const float4*)(h1b + cur * 768 + 1 * 256);
      const float4* r2 = (const float4*)(h1b + cur * 768 + 2 * 256);

      #pragma unroll
      for (int j = 0; j < 16; ++j) {
        const int s = j & 3;
        float4 w0 = R[s][0], w1 = R[s][1], w2 = R[s][2], w3 = R[s][3];
        const int jn = (j + 3) & 15;
        R[(j + 3) & 3][0] = wq[(jn * 4 + 0) * 256];
        R[(j + 3) & 3][1] = wq[(jn * 4 + 1) * 256];
        R[(j + 3) & 3][2] = wq[(jn * 4 + 2) * 256];
        R[(j + 3) & 3][3] = wq[(jn * 4 + 3) * 256];
        float4 hA0 = r0[2 * j], hB0 = r0[2 * j + 1];
        float4 hA1 = r1[2 * j], hB1 = r1[2 * j + 1];
        float4 hA2 = r2[2 * j], hB2 = r2[2 * j + 1];
        const v2h* a = (const v2h*)&hA0; const v2h* bb_ = (const v2h*)&hB0;
        dotg2(w0, a[0], a[1], a0[0], a1[0]);
        dotg2(w1, a[2], a[3], a0[0], a1[0]);
        dotg2(w2, bb_[0], bb_[1], a0[0], a1[0]);
        dotg2(w3, bb_[2], bb_[3], a0[0], a1[0]);
        a = (const v2h*)&hA1; bb_ = (const v2h*)&hB1;
        dotg2(w0, a[0], a[1], a0[1], a1[1]);
        dotg2(w1, a[2], a[3], a0[1], a1[1]);
        dotg2(w2, bb_[0], bb_[1], a0[1], a1[1]);
        dotg2(w3, bb_[2], bb_[3], a0[1], a1[1]);
        a = (const v2h*)&hA2; bb_ = (const v2h*)&hB2;
        dotg2(w0, a[0], a[1], a0[2], a1[2]);
        dotg2(w1, a[2], a[3], a0[2], a1[2]);
        dotg2(w2, bb_[0], bb_[1], a0[2], a1[2]);
        dotg2(w3, bb_[2], bb_[3], a0[2], a1[2]);
      }

      const int t = kc * Tc + tc;
      #pragma unroll
      for (int b = 0; b < 3; ++b) {
        float p0 = __shfl_xor(a0[b], 1);
        float p1 = __shfl_xor(a1[b], 1);
        float gi = gp ? p0 : a0[b];
        float gf = gp ? p1 : a1[b];
        float gg = gp ? a0[b] : p0;
        float go = gp ? a1[b] : p1;
        c[b] = sigf(gf) * c[b] + sigf(gi) * tanhf_fast(gg);
        float h = sigf(go) * tanhf_fast(c[b]);
        hout[b] = h;
        if (gp == 0) {
          h1b[nxt * 768 + b * 256 + u] = __half_as_ushort(__float2half(h));
          if (t == len[b] - 1) ws[OFF_HLAST + (bg + b) * 256 + u] = h;
        }
        xc[b] = xn[b];
      }
      lds_barrier();
    }
    if (gp == 0) {
      #pragma unroll
      for (int b = 0; b < 3; ++b) {
        ws[OFF_C1S + (bg + b) * 256 + u] = c[b];
        ws[OFF_H1S + (bg + b) * 256 + u] = hout[b];
      }
    }

  } else {
    // ===== role: gemm xp1 = W_ih1 @ h0 + b1, chunk kc = step-1 ============
    if (step < 1 || step >= NCHUNK + 1) return;
    if (bid >= 236) return;
    const int kc = step - 1;
    const int gid = bid - 172;  // [0,64)
    const int b0g = gid * 4;    // 4 batches per block
    const int rt = tid & 63, wv = tid >> 6;
    __half2* hc2 = (__half2*)smem_raw;  // [128 p][128 col]

    int lmax = 0;
    #pragma unroll
    for (int i = 0; i < 4; ++i) lmax = max(lmax, lengths[b0g + i]);
    if (kc * Tc >= lmax) return;
    const int slot = kc & 1;

    {
      const unsigned short* src =
          h0cS + (size_t)slot * H0SLOT + (size_t)b0g * 8192;
      const int cl = tid & 127, pg = tid >> 7;
      #pragma unroll
      for (int pp = 0; pp < 32; pp += 4) {
        const int p0 = pg * 32 + pp;
        uint4 v = *(const uint4*)(src + (size_t)cl * 256 + p0 * 2);
        unsigned* d = (unsigned*)hc2;
        d[(p0 + 0) * 128 + cl] = v.x;
        d[(p0 + 1) * 128 + cl] = v.y;
        d[(p0 + 2) * 128 + cl] = v.z;
        d[(p0 + 3) * 128 + cl] = v.w;
      }
    }
    __syncthreads();

    const __half* Wb = h16 + H_IH1;  // [p][u][g][2]
    unsigned short* xdst = xpS + (size_t)slot * XPSLOT;
    #pragma unroll 1
    for (int rp = 0; rp < 2; ++rp) {
      #pragma unroll 1
      for (int cp = 0; cp < 2; ++cp) {
        const int uA = rp * 128 + rt, uB = uA + 64;
        const int c0 = cp * 64 + wv * 8;
        const float4 bA = ((const float4*)(ws + OFF_B1))[uA];
        const float4 bB = ((const float4*)(ws + OFF_B1))[uB];
        float accA[4][8], accB[4][8];
        #pragma unroll
        for (int g = 0; g < 4; ++g)
          #pragma unroll
          for (int cc = 0; cc < 8; ++cc) {
            accA[g][cc] = ((const float*)&bA)[g];
            accB[g][cc] = ((const float*)&bB)[g];
          }
        #pragma unroll 2
        for (int p = 0; p < 128; ++p) {
          float4 wA = *(const float4*)(Wb + (size_t)p * 2048 + uA * 8);
          float4 wB = *(const float4*)(Wb + (size_t)p * 2048 + uB * 8);
          float4 h0v = *(const float4*)(hc2 + p * 128 + c0);
          float4 h1v = *(const float4*)(hc2 + p * 128 + c0 + 4);
          const v2h* ga = (const v2h*)&wA;
          const v2h* gb = (const v2h*)&wB;
          const v2h* hv = (const v2h*)&h0v;
          const v2h* hw = (const v2h*)&h1v;
          #pragma unroll
          for (int g = 0; g < 4; ++g) {
            #pragma unroll
            for (int cc = 0; cc < 4; ++cc) {
              accA[g][cc] = __builtin_amdgcn_fdot2(ga[g], hv[cc], accA[g][cc], false);
              accA[g][cc + 4] = __builtin_amdgcn_fdot2(ga[g], hw[cc], accA[g][cc + 4], false);
              accB[g][cc] = __builtin_amdgcn_fdot2(gb[g], hv[cc], accB[g][cc], false);
              accB[g][cc + 4] = __builtin_amdgcn_fdot2(gb[g], hw[cc], accB[g][cc + 4], false);
            }
          }
        }
        #pragma unroll
        for (int cc = 0; cc < 8; ++cc) {
          const int col = c0 + cc;
          const size_t cb = ((size_t)(b0g + (col >> 5)) * 32 + (col & 31)) * 1024;
          ushort4 oA, oB;
          oA.x = __half_as_ushort(__float2half(accA[0][cc]));
          oA.y = __half_as_ushort(__float2half(accA[1][cc]));
          oA.z = __half_as_ushort(__float2half(accA[2][cc]));
          oA.w = __half_as_ushort(__float2half(accA[3][cc]));
          oB.x = __half_as_ushort(__float2half(accB[0][cc]));
          oB.y = __half_as_ushort(__float2half(accB[1][cc]));
          oB.z = __half_as_ushort(__float2half(accB[2][cc]));
          oB.w = __half_as_ushort(__float2half(accB[3][cc]));
          *(ushort4*)(xdst + cb + uA * 4) = oA;
          *(ushort4*)(xdst + cb + uB * 4) = oB;
        }
      }
    }
  }
}

__global__ __launch_bounds__(256) void fc_kernel(
    const float* __restrict__ ws, const float* __restrict__ fc_w,
    const float* __restrict__ fc_b, float* __restrict__ out) {
  __shared__ float red[256];
  const int tid = threadIdx.x;
  const int b = blockIdx.x;
  red[tid] = fmaxf(ws[OFF_HLAST + b * 256 + tid], 0.f) * fc_w[tid];
  __syncthreads();
  #pragma unroll
  for (int s = 128; s > 0; s >>= 1) {
    if (tid < s) red[tid] += red[tid + s];
    __syncthreads();
  }
  if (tid == 0) out[b] = red[0] + fc_b[0];
}

extern "C" void kernel_launch(void* const* d_in, const int* in_sizes, int n_in,
                              void* d_out, int out_size, void* d_ws, size_t ws_size,
                              hipStream_t stream) {
  const float* x     = (const float*)d_in[0];
  const int*   lens  = (const int*)d_in[1];
  const float* w_ih0 = (const float*)d_in[2];
  const float* w_hh0 = (const float*)d_in[3];
  const float* b_ih0 = (const float*)d_in[4];
  const float* b_hh0 = (const float*)d_in[5];
  const float* w_ih1 = (const float*)d_in[6];
  const float* w_hh1 = (const float*)d_in[7];
  const float* b_ih1 = (const float*)d_in[8];
  const float* b_hh1 = (const float*)d_in[9];
  const float* fc_w  = (const float*)d_in[10];
  const float* fc_b  = (const float*)d_in[11];
  float* out = (float*)d_out;
  float* ws  = (float*)d_ws;

  hipLaunchKernelGGL(prep_kernel, dim3(512), dim3(256), 0, stream,
                     w_ih0, w_hh0, b_ih0, b_hh0, w_ih1, w_hh1, b_ih1, b_hh1, ws);
  hipFuncSetAttribute(reinterpret_cast<const void*>(fused_kernel),
                      hipFuncAttributeMaxDynamicSharedMemorySize, SMEM_BYTES);
  for (int k = 0; k < NCHUNK + 2; ++k) {
    hipLaunchKernelGGL(fused_kernel, dim3(236), dim3(512), SMEM_BYTES, stream,
                       ws, x, lens, k);
  }
  hipLaunchKernelGGL(fc_kernel, dim3(256), dim3(256), 0, stream,
                     ws, fc_w, fc_b, out);
}